// Round 1
// baseline (426.404 us; speedup 1.0000x reference)
//
#include <hip/hip_runtime.h>

typedef __attribute__((ext_vector_type(8))) short short8;
typedef __attribute__((ext_vector_type(4))) short s4v;
typedef __attribute__((ext_vector_type(4))) float floatx4;

#define ROWQ 264   // 256 + 8 bf16 pad -> 528B row stride, 16B aligned

// round-to-nearest-even fp32 -> bf16 bits
__device__ __forceinline__ unsigned short f2bf(float f) {
    unsigned u = __float_as_uint(f);
    u += 0x7fffu + ((u >> 16) & 1u);
    return (unsigned short)(u >> 16);
}

// Closed form of the 128 sequential where-passes:
//  |x|>=1 (gate |y|<1 always false): g-table, last-match-wins =>
//    e = floor(log2 a) + (mant>1.875), clamp 15; t2 = a*2^-e in (0.9375,1.875]
//    t2<1.0625 -> 2^e ; else j=floor((t2-1.0625)*8)+1 -> (1+0.125j)*2^e
//    exact interval boundaries (open intervals) -> unchanged
//  |x|<1 (gate always true): l-table only =>
//    a<1.0625*2^-16 -> sign*2^-16 ; mant in [1,1.0625] or [1.9375,2) -> unchanged (gaps)
//    else quantize mantissa the same way at scale 2^floor(log2 a)
__device__ __forceinline__ float posit_q(float x) {
    unsigned xu = __float_as_uint(x);
    unsigned au = xu & 0x7fffffffu;
    if (au == 0u) return x;
    float a = __uint_as_float(au);
    unsigned sgn = xu & 0x80000000u;
    if (a >= 1.0f) {
        int E = (int)(au >> 23) - 127;
        float t = __uint_as_float((au & 0x007fffffu) | 0x3f800000u);
        int e = E + ((t > 1.875f) ? 1 : 0);
        if (e > 15) e = 15;
        float t2 = a * __uint_as_float((unsigned)(127 - e) << 23); // exact
        if (t2 >= 1.9375f) return x;     // only when clamped at e=15
        float val;
        if (t2 < 1.0625f) {
            val = 1.0f;                  // covers (0.9375, 1.0625)
        } else {
            float rj = (t2 - 1.0625f) * 8.0f;   // exact (Sterbenz)
            float fj = floorf(rj);
            if (rj == fj) return x;      // open-interval boundary point
            val = fmaf(0.125f, fj + 1.0f, 1.0f);
        }
        float res = val * __uint_as_float((unsigned)(127 + e) << 23);
        return __uint_as_float(__float_as_uint(res) | sgn);
    } else {
        if (a < 0x1.1p-16f)              // (0, 1.0625*2^-16) -> 2^-16
            return __uint_as_float(sgn | __float_as_uint(0x1.0p-16f));
        int E = (int)(au >> 23) - 127;   // in [-16,-1]
        float t = __uint_as_float((au & 0x007fffffu) | 0x3f800000u);
        if (t <= 1.0625f || t >= 1.9375f) return x;  // gap around powers of 2
        float rj = (t - 1.0625f) * 8.0f;
        float fj = floorf(rj);
        if (rj == fj) return x;
        float val = fmaf(0.125f, fj + 1.0f, 1.0f);
        float res = val * __uint_as_float((unsigned)(127 + E) << 23);
        return __uint_as_float(__float_as_uint(res) | sgn);
    }
}

// quantize weights to bf16, fold conv bias + BN into per-channel scale/bias
__global__ __launch_bounds__(256) void prep_kernel(
    const float* __restrict__ w1, const float* __restrict__ w2,
    const float* __restrict__ b1, const float* __restrict__ g1,
    const float* __restrict__ be1, const float* __restrict__ m1,
    const float* __restrict__ v1,
    const float* __restrict__ b2, const float* __restrict__ g2,
    const float* __restrict__ be2, const float* __restrict__ m2,
    const float* __restrict__ v2,
    unsigned short* __restrict__ w1q, unsigned short* __restrict__ w2q,
    float* __restrict__ cst)
{
    int i = blockIdx.x * 256 + threadIdx.x;
    if (i < 65536) {
        w1q[i] = f2bf(posit_q(w1[i]));
        w2q[i] = f2bf(posit_q(w2[i]));
        if (i < 256) {
            float inv1 = g1[i] / sqrtf(v1[i] + 1e-5f);
            cst[i]       = inv1;
            cst[256 + i] = fmaf(b1[i], inv1, be1[i] - m1[i] * inv1);
            float inv2 = g2[i] / sqrtf(v2[i] + 1e-5f);
            cst[512 + i] = inv2;
            cst[768 + i] = fmaf(b2[i], inv2, be2[i] - m2[i] * inv2);
        }
    }
}

// One block: 64 positions x all 256 channels; both GEMMs fused through LDS.
__global__ __launch_bounds__(256, 2) void fused_kernel(
    const float* __restrict__ x,
    const unsigned short* __restrict__ w1q,
    const unsigned short* __restrict__ w2q,
    const float* __restrict__ cst,
    float* __restrict__ out)
{
    __shared__ alignas(16) unsigned short q[64 * ROWQ];

    const int b  = blockIdx.x;          // 2048 blocks
    const int n  = b >> 8;              // 256 s-blocks per batch image
    const int s0 = (b & 255) << 6;
    const float* xb = x   + (size_t)n * (256 * 16384) + s0;
    float*       ob = out + (size_t)n * (256 * 16384) + s0;

    const int t    = threadIdx.x;
    const int lane = t & 63;
    const int w    = t >> 6;            // wave id 0..3 -> out-channel rows 64w..64w+63
    const int quad = lane >> 4;
    const int l15  = lane & 15;

    // ---- Phase 1: global fp32 -> posit_q -> bf16 -> LDS q[p][c] (transpose) ----
    {
        const int p = t & 63;
        const int g = t >> 6;
        #pragma unroll
        for (int it = 0; it < 8; ++it) {
            const int c0 = it * 32 + g * 8;
            float v[8];
            #pragma unroll
            for (int j = 0; j < 8; ++j)
                v[j] = xb[(size_t)(c0 + j) * 16384 + p];
            short8 pk;
            #pragma unroll
            for (int j = 0; j < 8; ++j)
                pk[j] = (short)f2bf(posit_q(v[j]));
            *(short8*)&q[p * ROWQ + c0] = pk;
        }
    }
    __syncthreads();

    const int mbase = w * 64;
    floatx4 acc[4][4];
    #pragma unroll
    for (int i = 0; i < 4; ++i)
        #pragma unroll
        for (int jj = 0; jj < 4; ++jj)
            acc[i][jj] = (floatx4)0.0f;

    // ---- GEMM1: A = W1q (global, L2-hot), B = q ----
    #pragma unroll
    for (int kk = 0; kk < 256; kk += 32) {
        short8 af[4], bf[4];
        #pragma unroll
        for (int i = 0; i < 4; ++i)
            af[i] = *(const short8*)&w1q[(size_t)(mbase + 16 * i + l15) * 256 + kk + quad * 8];
        #pragma unroll
        for (int jj = 0; jj < 4; ++jj)
            bf[jj] = *(const short8*)&q[(16 * jj + l15) * ROWQ + kk + quad * 8];
        #pragma unroll
        for (int i = 0; i < 4; ++i)
            #pragma unroll
            for (int jj = 0; jj < 4; ++jj)
                acc[i][jj] = __builtin_amdgcn_mfma_f32_16x16x32_bf16(af[i], bf[jj], acc[i][jj], 0, 0, 0);
    }
    __syncthreads();   // all waves done reading q before we overwrite it

    // ---- Epilogue 1: BN1 + ReLU + posit_q -> bf16 back into q[p][m] ----
    {
        const float* sc1 = cst;
        const float* bi1 = cst + 256;
        #pragma unroll
        for (int i = 0; i < 4; ++i) {
            const int m0 = mbase + 16 * i + quad * 4;
            float sc[4], bi[4];
            #pragma unroll
            for (int r = 0; r < 4; ++r) { sc[r] = sc1[m0 + r]; bi[r] = bi1[m0 + r]; }
            #pragma unroll
            for (int jj = 0; jj < 4; ++jj) {
                const int p = 16 * jj + l15;
                s4v h;
                #pragma unroll
                for (int r = 0; r < 4; ++r) {
                    float z = fmaf(acc[i][jj][r], sc[r], bi[r]);
                    z = fmaxf(z, 0.0f);
                    h[r] = (short)f2bf(posit_q(z));
                }
                *(s4v*)&q[p * ROWQ + m0] = h;
            }
        }
    }
    __syncthreads();

    // ---- GEMM2: A = W2q, B = q (now holds quantized z1) ----
    #pragma unroll
    for (int i = 0; i < 4; ++i)
        #pragma unroll
        for (int jj = 0; jj < 4; ++jj)
            acc[i][jj] = (floatx4)0.0f;

    #pragma unroll
    for (int kk = 0; kk < 256; kk += 32) {
        short8 af[4], bf[4];
        #pragma unroll
        for (int i = 0; i < 4; ++i)
            af[i] = *(const short8*)&w2q[(size_t)(mbase + 16 * i + l15) * 256 + kk + quad * 8];
        #pragma unroll
        for (int jj = 0; jj < 4; ++jj)
            bf[jj] = *(const short8*)&q[(16 * jj + l15) * ROWQ + kk + quad * 8];
        #pragma unroll
        for (int i = 0; i < 4; ++i)
            #pragma unroll
            for (int jj = 0; jj < 4; ++jj)
                acc[i][jj] = __builtin_amdgcn_mfma_f32_16x16x32_bf16(af[i], bf[jj], acc[i][jj], 0, 0, 0);
    }

    // ---- Epilogue 2: BN2 + residual + ReLU -> out ----
    {
        const float* sc2 = cst + 512;
        const float* bi2 = cst + 768;
        #pragma unroll
        for (int i = 0; i < 4; ++i) {
            const int m0 = mbase + 16 * i + quad * 4;
            float sc[4], bi[4];
            #pragma unroll
            for (int r = 0; r < 4; ++r) { sc[r] = sc2[m0 + r]; bi[r] = bi2[m0 + r]; }
            #pragma unroll
            for (int jj = 0; jj < 4; ++jj) {
                const int p = 16 * jj + l15;
                #pragma unroll
                for (int r = 0; r < 4; ++r) {
                    const size_t off = (size_t)(m0 + r) * 16384 + p;
                    float v = fmaf(acc[i][jj][r], sc[r], bi[r]);
                    v += xb[off];                  // residual (original fp32 x)
                    ob[off] = fmaxf(v, 0.0f);
                }
            }
        }
    }
}

extern "C" void kernel_launch(void* const* d_in, const int* in_sizes, int n_in,
                              void* d_out, int out_size, void* d_ws, size_t ws_size,
                              hipStream_t stream) {
    const float* x   = (const float*)d_in[0];
    const float* w1  = (const float*)d_in[1];
    const float* b1  = (const float*)d_in[2];
    const float* g1  = (const float*)d_in[3];
    const float* be1 = (const float*)d_in[4];
    const float* m1  = (const float*)d_in[5];
    const float* v1  = (const float*)d_in[6];
    const float* w2  = (const float*)d_in[7];
    const float* b2  = (const float*)d_in[8];
    const float* g2  = (const float*)d_in[9];
    const float* be2 = (const float*)d_in[10];
    const float* m2  = (const float*)d_in[11];
    const float* v2  = (const float*)d_in[12];

    unsigned short* w1q = (unsigned short*)d_ws;
    unsigned short* w2q = w1q + 65536;
    float* cst = (float*)(w2q + 65536);   // scale1|bias1|scale2|bias2 (4*256 floats)

    prep_kernel<<<256, 256, 0, stream>>>(w1, w2, b1, g1, be1, m1, v1,
                                         b2, g2, be2, m2, v2, w1q, w2q, cst);
    fused_kernel<<<2048, 256, 0, stream>>>(x, w1q, w2q, cst, (float*)d_out);
}

// Round 2
// 397.779 us; speedup vs baseline: 1.0720x; 1.0720x over previous
//
#include <hip/hip_runtime.h>

typedef __attribute__((ext_vector_type(8))) short short8;
typedef __attribute__((ext_vector_type(4))) short s4v;
typedef __attribute__((ext_vector_type(4))) float floatx4;

#define SPOS 16384

// round-to-nearest-even fp32 -> bf16 bits
__device__ __forceinline__ unsigned short f2bf(float f) {
    unsigned u = __float_as_uint(f);
    u += 0x7fffu + ((u >> 16) & 1u);
    return (unsigned short)(u >> 16);
}

// Branchless bit-twiddle posit quantizer — exactly equivalent to the verified
// closed form of the 128 sequential where-passes:
//   core: round mantissa to nearest 1/8: (au + 0x80000) & ~0xFFFFF
//   exceptions:
//    * interior boundary points (m&0xFFFFF)==0x80000 (open intervals) unchanged,
//      EXCEPT m==0x780000 for |x|>=1 (t=1.9375 -> 2^(E+1), carry handles it)
//    * |x|>=1, t in (1.875,1.9375): next-octave j=0 interval wins -> 2^(E+1)
//      (guard E<15 via au<0x47700000; clamp region au>=0x47780000 unchanged)
//    * |x|<1: mantissa gaps [1,1.0625] and [1.9375,2) unchanged;
//      (0, 1.0625*2^-16) -> sign*2^-16
__device__ __forceinline__ float posit_q(float x) {
    unsigned xu  = __float_as_uint(x);
    unsigned sgn = xu & 0x80000000u;
    unsigned au  = xu & 0x7fffffffu;
    unsigned m   = au & 0x007fffffu;
    unsigned r   = (au + 0x00080000u) & 0xfff00000u;
    bool bdry = (m & 0x000fffffu) == 0x00080000u;
    unsigned res;
    if (au >= 0x3f800000u) {                      // |x| >= 1
        res = r;
        if (m > 0x00700000u && m < 0x00780000u && au < 0x47700000u)
            res = (au & 0xff800000u) + 0x00800000u;   // -> 2^(E+1)
        if ((bdry && m != 0x00780000u) || au >= 0x47780000u)
            res = au;                              // boundaries & clamp unchanged
    } else {                                       // |x| < 1
        res = (m <= 0x00080000u || m >= 0x00780000u || bdry) ? au : r;
        if (au < 0x37880000u) res = au ? 0x37800000u : 0u;  // -> 2^-16 (0 stays 0)
    }
    return __uint_as_float(sgn | res);
}

// quantize weights to bf16, fold conv bias + BN into per-channel scale/bias
__global__ __launch_bounds__(256) void prep_kernel(
    const float* __restrict__ w1, const float* __restrict__ w2,
    const float* __restrict__ b1, const float* __restrict__ g1,
    const float* __restrict__ be1, const float* __restrict__ m1,
    const float* __restrict__ v1,
    const float* __restrict__ b2, const float* __restrict__ g2,
    const float* __restrict__ be2, const float* __restrict__ m2,
    const float* __restrict__ v2,
    unsigned short* __restrict__ w1q, unsigned short* __restrict__ w2q,
    float* __restrict__ cst)
{
    int i = blockIdx.x * 256 + threadIdx.x;
    if (i < 65536) {
        w1q[i] = f2bf(posit_q(w1[i]));
        w2q[i] = f2bf(posit_q(w2[i]));
        if (i < 256) {
            float inv1 = g1[i] / sqrtf(v1[i] + 1e-5f);
            cst[i]       = inv1;
            cst[256 + i] = fmaf(b1[i], inv1, be1[i] - m1[i] * inv1);
            float inv2 = g2[i] / sqrtf(v2[i] + 1e-5f);
            cst[512 + i] = inv2;
            cst[768 + i] = fmaf(b2[i], inv2, be2[i] - m2[i] * inv2);
        }
    }
}

// q layout: 64 rows (positions/out-rows) x 32 column-blocks of 8 bf16.
// Column-block cb stored at physical block (cb ^ (p & 31)) -> all LDS ops
// (b128 reads/writes, b64 epilogue writes) are bank-balanced at minimum.
__device__ __forceinline__ int qidx(int p, int cb) {
    return p * 256 + ((cb ^ (p & 31)) << 3);
}

// One block: 64 positions x all 256 channels; both GEMMs fused through LDS.
__global__ __launch_bounds__(256, 3) void fused_kernel(
    const float* __restrict__ x,
    const unsigned short* __restrict__ w1q,
    const unsigned short* __restrict__ w2q,
    const float* __restrict__ cst,
    float* __restrict__ out)
{
    __shared__ alignas(16) unsigned short q[64 * 256];  // 32 KB, swizzled
    __shared__ alignas(16) float xs[64 * 64];           // 16 KB, [c_local][p]

    const int b  = blockIdx.x;          // 2048 blocks
    const int n  = b >> 8;
    const int s0 = (b & 255) << 6;
    const float* xb = x   + (size_t)n * (256 * SPOS) + s0;
    float*       ob = out + (size_t)n * (256 * SPOS) + s0;

    const int t    = threadIdx.x;
    const int lane = t & 63;
    const int w    = t >> 6;            // wave id 0..3
    const int quad = lane >> 4;
    const int l15  = lane & 15;

    // ---- Phase 1: x -> posit_q -> bf16 -> swizzled q, in 4 quarters of 64 ch ----
    {
        const int g   = t & 15;         // position 4-group for stage A
        const int ca  = t >> 4;         // channel-within-round for stage A
        for (int qt = 0; qt < 4; ++qt) {
            #pragma unroll
            for (int r = 0; r < 4; ++r) {
                const int cl = r * 16 + ca;
                const float4 v = *(const float4*)&xb[(size_t)(qt * 64 + cl) * SPOS + 4 * g];
                *(float4*)&xs[cl * 64 + 4 * g] = v;
            }
            __syncthreads();
            {
                const int p  = lane;    // each wave: 16 channels x 64 positions
                const int c0 = w * 16;
                short8 pk0, pk1;
                #pragma unroll
                for (int j = 0; j < 8; ++j) {
                    pk0[j] = (short)f2bf(posit_q(xs[(c0 + j) * 64 + p]));
                    pk1[j] = (short)f2bf(posit_q(xs[(c0 + 8 + j) * 64 + p]));
                }
                const int cb0 = qt * 8 + w * 2;
                *(short8*)&q[qidx(p, cb0)]     = pk0;
                *(short8*)&q[qidx(p, cb0 + 1)] = pk1;
            }
            __syncthreads();            // xs reusable next quarter; q ready after last
        }
    }

    const int mbase = w * 64;
    floatx4 acc[4][4];
    #pragma unroll
    for (int i = 0; i < 4; ++i)
        #pragma unroll
        for (int jj = 0; jj < 4; ++jj)
            acc[i][jj] = (floatx4)0.0f;

    // ---- GEMM1: A = W1q (global, L2-hot), B = q ----
    #pragma unroll
    for (int kk = 0; kk < 256; kk += 32) {
        short8 af[4], bf[4];
        #pragma unroll
        for (int i = 0; i < 4; ++i)
            af[i] = *(const short8*)&w1q[(size_t)(mbase + 16 * i + l15) * 256 + kk + quad * 8];
        #pragma unroll
        for (int jj = 0; jj < 4; ++jj)
            bf[jj] = *(const short8*)&q[qidx(16 * jj + l15, (kk >> 3) + quad)];
        #pragma unroll
        for (int i = 0; i < 4; ++i)
            #pragma unroll
            for (int jj = 0; jj < 4; ++jj)
                acc[i][jj] = __builtin_amdgcn_mfma_f32_16x16x32_bf16(af[i], bf[jj], acc[i][jj], 0, 0, 0);
    }
    __syncthreads();   // all waves done reading q before overwrite

    // ---- Epilogue 1: BN1 + ReLU + posit_q -> bf16 back into q[p][m] ----
    {
        const float* sc1 = cst;
        const float* bi1 = cst + 256;
        #pragma unroll
        for (int i = 0; i < 4; ++i) {
            const int m0 = mbase + 16 * i + quad * 4;
            float sc[4], bi[4];
            #pragma unroll
            for (int r = 0; r < 4; ++r) { sc[r] = sc1[m0 + r]; bi[r] = bi1[m0 + r]; }
            #pragma unroll
            for (int jj = 0; jj < 4; ++jj) {
                const int p = 16 * jj + l15;
                s4v h;
                #pragma unroll
                for (int r = 0; r < 4; ++r) {
                    float z = fmaf(acc[i][jj][r], sc[r], bi[r]);
                    z = fmaxf(z, 0.0f);
                    h[r] = (short)f2bf(posit_q(z));
                }
                *(s4v*)&q[qidx(p, m0 >> 3) + (m0 & 7)] = h;
            }
        }
    }
    __syncthreads();

    // ---- GEMM2: A = W2q, B = q (quantized z1) ----
    #pragma unroll
    for (int i = 0; i < 4; ++i)
        #pragma unroll
        for (int jj = 0; jj < 4; ++jj)
            acc[i][jj] = (floatx4)0.0f;

    #pragma unroll
    for (int kk = 0; kk < 256; kk += 32) {
        short8 af[4], bf[4];
        #pragma unroll
        for (int i = 0; i < 4; ++i)
            af[i] = *(const short8*)&w2q[(size_t)(mbase + 16 * i + l15) * 256 + kk + quad * 8];
        #pragma unroll
        for (int jj = 0; jj < 4; ++jj)
            bf[jj] = *(const short8*)&q[qidx(16 * jj + l15, (kk >> 3) + quad)];
        #pragma unroll
        for (int i = 0; i < 4; ++i)
            #pragma unroll
            for (int jj = 0; jj < 4; ++jj)
                acc[i][jj] = __builtin_amdgcn_mfma_f32_16x16x32_bf16(af[i], bf[jj], acc[i][jj], 0, 0, 0);
    }

    // ---- Epilogue 2: BN2 + residual + ReLU -> out ----
    {
        const float* sc2 = cst + 512;
        const float* bi2 = cst + 768;
        #pragma unroll
        for (int i = 0; i < 4; ++i) {
            const int m0 = mbase + 16 * i + quad * 4;
            float sc[4], bi[4];
            #pragma unroll
            for (int r = 0; r < 4; ++r) { sc[r] = sc2[m0 + r]; bi[r] = bi2[m0 + r]; }
            #pragma unroll
            for (int jj = 0; jj < 4; ++jj) {
                const int p = 16 * jj + l15;
                #pragma unroll
                for (int r = 0; r < 4; ++r) {
                    const size_t off = (size_t)(m0 + r) * SPOS + p;
                    float v = fmaf(acc[i][jj][r], sc[r], bi[r]);
                    v += xb[off];                  // residual (L2-hot re-read)
                    ob[off] = fmaxf(v, 0.0f);
                }
            }
        }
    }
}

extern "C" void kernel_launch(void* const* d_in, const int* in_sizes, int n_in,
                              void* d_out, int out_size, void* d_ws, size_t ws_size,
                              hipStream_t stream) {
    const float* x   = (const float*)d_in[0];
    const float* w1  = (const float*)d_in[1];
    const float* b1  = (const float*)d_in[2];
    const float* g1  = (const float*)d_in[3];
    const float* be1 = (const float*)d_in[4];
    const float* m1  = (const float*)d_in[5];
    const float* v1  = (const float*)d_in[6];
    const float* w2  = (const float*)d_in[7];
    const float* b2  = (const float*)d_in[8];
    const float* g2  = (const float*)d_in[9];
    const float* be2 = (const float*)d_in[10];
    const float* m2  = (const float*)d_in[11];
    const float* v2  = (const float*)d_in[12];

    unsigned short* w1q = (unsigned short*)d_ws;
    unsigned short* w2q = w1q + 65536;
    float* cst = (float*)(w2q + 65536);   // scale1|bias1|scale2|bias2

    prep_kernel<<<256, 256, 0, stream>>>(w1, w2, b1, g1, be1, m1, v1,
                                         b2, g2, be2, m2, v2, w1q, w2q, cst);
    fused_kernel<<<2048, 256, 0, stream>>>(x, w1q, w2q, cst, (float*)d_out);
}

// Round 3
// 365.696 us; speedup vs baseline: 1.1660x; 1.0877x over previous
//
#include <hip/hip_runtime.h>

typedef __attribute__((ext_vector_type(8))) short short8;
typedef __attribute__((ext_vector_type(4))) short s4v;
typedef __attribute__((ext_vector_type(4))) float floatx4;

#define SPOS 16384

// round-to-nearest-even fp32 -> bf16 bits
__device__ __forceinline__ unsigned short f2bf(float f) {
    unsigned u = __float_as_uint(f);
    u += 0x7fffu + ((u >> 16) & 1u);
    return (unsigned short)(u >> 16);
}

// Branchless bit-twiddle posit quantizer (verified equivalent of the 128
// sequential where-passes; see R1/R2 derivation comments).
__device__ __forceinline__ float posit_q(float x) {
    unsigned xu  = __float_as_uint(x);
    unsigned sgn = xu & 0x80000000u;
    unsigned au  = xu & 0x7fffffffu;
    unsigned m   = au & 0x007fffffu;
    unsigned r   = (au + 0x00080000u) & 0xfff00000u;
    bool bdry = (m & 0x000fffffu) == 0x00080000u;
    unsigned res;
    if (au >= 0x3f800000u) {                      // |x| >= 1
        res = r;
        if (m > 0x00700000u && m < 0x00780000u && au < 0x47700000u)
            res = (au & 0xff800000u) + 0x00800000u;   // -> 2^(E+1)
        if ((bdry && m != 0x00780000u) || au >= 0x47780000u)
            res = au;                              // boundaries & clamp unchanged
    } else {                                       // |x| < 1
        res = (m <= 0x00080000u || m >= 0x00780000u || bdry) ? au : r;
        if (au < 0x37880000u) res = au ? 0x37800000u : 0u;  // -> 2^-16 (0 stays 0)
    }
    return __uint_as_float(sgn | res);
}

// quantize weights to bf16, fold conv bias + BN into per-channel scale/bias
__global__ __launch_bounds__(256) void prep_kernel(
    const float* __restrict__ w1, const float* __restrict__ w2,
    const float* __restrict__ b1, const float* __restrict__ g1,
    const float* __restrict__ be1, const float* __restrict__ m1,
    const float* __restrict__ v1,
    const float* __restrict__ b2, const float* __restrict__ g2,
    const float* __restrict__ be2, const float* __restrict__ m2,
    const float* __restrict__ v2,
    unsigned short* __restrict__ w1q, unsigned short* __restrict__ w2q,
    float* __restrict__ cst)
{
    int i = blockIdx.x * 256 + threadIdx.x;
    if (i < 65536) {
        w1q[i] = f2bf(posit_q(w1[i]));
        w2q[i] = f2bf(posit_q(w2[i]));
        if (i < 256) {
            float inv1 = g1[i] / sqrtf(v1[i] + 1e-5f);
            cst[i]       = inv1;
            cst[256 + i] = fmaf(b1[i], inv1, be1[i] - m1[i] * inv1);
            float inv2 = g2[i] / sqrtf(v2[i] + 1e-5f);
            cst[512 + i] = inv2;
            cst[768 + i] = fmaf(b2[i], inv2, be2[i] - m2[i] * inv2);
        }
    }
}

// q layout: 64 rows (p) x 32 column-blocks of 8 bf16, XOR-swizzled:
// block cb stored at physical block (cb ^ (p & 31)) -> all LDS ops bank-minimal.
__device__ __forceinline__ int qidx(int p, int cb) {
    return p * 256 + ((cb ^ (p & 31)) << 3);
}

// One block: 64 positions x all 256 channels; both GEMMs fused through LDS.
// LDS = 32 KB (q) + 8 KB (xs) = 40960 B exactly -> 4 blocks/CU.
__global__ __launch_bounds__(256, 4) void fused_kernel(
    const float* __restrict__ x,
    const unsigned short* __restrict__ w1q,
    const unsigned short* __restrict__ w2q,
    const float* __restrict__ cst,
    float* __restrict__ out)
{
    __shared__ alignas(16) unsigned short q[64 * 256];  // 32 KB, swizzled
    __shared__ alignas(16) float xs[4 * 512];           // 8 KB, wave-private strips

    const int b  = blockIdx.x;          // 2048 blocks
    const int n  = b >> 8;
    const int s0 = (b & 255) << 6;
    const float* xb = x   + (size_t)n * (256 * SPOS) + s0;
    float*       ob = out + (size_t)n * (256 * SPOS) + s0;

    const int t    = threadIdx.x;
    const int lane = t & 63;
    const int w    = t >> 6;            // wave id 0..3
    const int quad = lane >> 4;
    const int l15  = lane & 15;

    // ---- Phase 1 (NO barriers): wave w owns channels 64w..64w+63.
    // 8 rounds x 8 channels; xs strip is wave-private; swizzled so both the
    // float4 writes and the b32 column reads are bank-minimal.
    {
        const int g  = lane & 15;       // float4 group along p
        const int co = lane >> 4;       // 0..3
        float* xsw = xs + w * 512;
        const float* src0 = xb + (size_t)(64 * w + co) * SPOS + 4 * g;
        #pragma unroll
        for (int r = 0; r < 8; ++r) {
            const float4 v0 = *(const float4*)(src0 + (size_t)(8 * r) * SPOS);
            const float4 v1 = *(const float4*)(src0 + (size_t)(8 * r + 4) * SPOS);
            // element p of channel-row cl lives at dword cl*64 + (p ^ 4*cl)
            *(float4*)&xsw[co * 64 + ((4 * g) ^ (4 * co))]             = v0;
            *(float4*)&xsw[(co + 4) * 64 + ((4 * g) ^ (4 * (co + 4)))] = v1;
            short8 pk;
            #pragma unroll
            for (int c8 = 0; c8 < 8; ++c8)
                pk[c8] = (short)f2bf(posit_q(xsw[c8 * 64 + (lane ^ (4 * c8))]));
            *(short8*)&q[qidx(lane, 8 * w + r)] = pk;   // cb = (64w+8r)/8
        }
    }
    __syncthreads();    // q fully populated

    const int mbase = w * 64;
    floatx4 acc[4][4];
    #pragma unroll
    for (int i = 0; i < 4; ++i)
        #pragma unroll
        for (int jj = 0; jj < 4; ++jj)
            acc[i][jj] = (floatx4)0.0f;

    // ---- GEMM1: A = W1q (global, L2-hot), B = q ----
    #pragma unroll
    for (int kk = 0; kk < 256; kk += 32) {
        short8 af[4], bf[4];
        #pragma unroll
        for (int i = 0; i < 4; ++i)
            af[i] = *(const short8*)&w1q[(size_t)(mbase + 16 * i + l15) * 256 + kk + quad * 8];
        #pragma unroll
        for (int jj = 0; jj < 4; ++jj)
            bf[jj] = *(const short8*)&q[qidx(16 * jj + l15, (kk >> 3) + quad)];
        #pragma unroll
        for (int i = 0; i < 4; ++i)
            #pragma unroll
            for (int jj = 0; jj < 4; ++jj)
                acc[i][jj] = __builtin_amdgcn_mfma_f32_16x16x32_bf16(af[i], bf[jj], acc[i][jj], 0, 0, 0);
    }
    __syncthreads();   // all waves done reading q before overwrite

    // ---- Epilogue 1: BN1 + ReLU + posit_q -> bf16 back into q[p][m] ----
    {
        const float* sc1 = cst;
        const float* bi1 = cst + 256;
        #pragma unroll
        for (int i = 0; i < 4; ++i) {
            const int m0 = mbase + 16 * i + quad * 4;
            float sc[4], bi[4];
            #pragma unroll
            for (int r = 0; r < 4; ++r) { sc[r] = sc1[m0 + r]; bi[r] = bi1[m0 + r]; }
            #pragma unroll
            for (int jj = 0; jj < 4; ++jj) {
                const int p = 16 * jj + l15;
                s4v h;
                #pragma unroll
                for (int r = 0; r < 4; ++r) {
                    float z = fmaf(acc[i][jj][r], sc[r], bi[r]);
                    z = fmaxf(z, 0.0f);
                    h[r] = (short)f2bf(posit_q(z));
                }
                *(s4v*)&q[qidx(p, m0 >> 3) + (m0 & 7)] = h;
            }
        }
    }
    __syncthreads();

    // ---- GEMM2: A = W2q, B = q (quantized z1) ----
    #pragma unroll
    for (int i = 0; i < 4; ++i)
        #pragma unroll
        for (int jj = 0; jj < 4; ++jj)
            acc[i][jj] = (floatx4)0.0f;

    #pragma unroll
    for (int kk = 0; kk < 256; kk += 32) {
        short8 af[4], bf[4];
        #pragma unroll
        for (int i = 0; i < 4; ++i)
            af[i] = *(const short8*)&w2q[(size_t)(mbase + 16 * i + l15) * 256 + kk + quad * 8];
        #pragma unroll
        for (int jj = 0; jj < 4; ++jj)
            bf[jj] = *(const short8*)&q[qidx(16 * jj + l15, (kk >> 3) + quad)];
        #pragma unroll
        for (int i = 0; i < 4; ++i)
            #pragma unroll
            for (int jj = 0; jj < 4; ++jj)
                acc[i][jj] = __builtin_amdgcn_mfma_f32_16x16x32_bf16(af[i], bf[jj], acc[i][jj], 0, 0, 0);
    }

    // ---- Epilogue 2: BN2 + residual + ReLU -> out ----
    {
        const float* sc2 = cst + 512;
        const float* bi2 = cst + 768;
        #pragma unroll
        for (int i = 0; i < 4; ++i) {
            const int m0 = mbase + 16 * i + quad * 4;
            float sc[4], bi[4];
            #pragma unroll
            for (int r = 0; r < 4; ++r) { sc[r] = sc2[m0 + r]; bi[r] = bi2[m0 + r]; }
            #pragma unroll
            for (int jj = 0; jj < 4; ++jj) {
                const int p = 16 * jj + l15;
                #pragma unroll
                for (int r = 0; r < 4; ++r) {
                    const size_t off = (size_t)(m0 + r) * SPOS + p;
                    float v = fmaf(acc[i][jj][r], sc[r], bi[r]);
                    v += xb[off];                  // residual (L2-hot re-read)
                    ob[off] = fmaxf(v, 0.0f);
                }
            }
        }
    }
}

extern "C" void kernel_launch(void* const* d_in, const int* in_sizes, int n_in,
                              void* d_out, int out_size, void* d_ws, size_t ws_size,
                              hipStream_t stream) {
    const float* x   = (const float*)d_in[0];
    const float* w1  = (const float*)d_in[1];
    const float* b1  = (const float*)d_in[2];
    const float* g1  = (const float*)d_in[3];
    const float* be1 = (const float*)d_in[4];
    const float* m1  = (const float*)d_in[5];
    const float* v1  = (const float*)d_in[6];
    const float* w2  = (const float*)d_in[7];
    const float* b2  = (const float*)d_in[8];
    const float* g2  = (const float*)d_in[9];
    const float* be2 = (const float*)d_in[10];
    const float* m2  = (const float*)d_in[11];
    const float* v2  = (const float*)d_in[12];

    unsigned short* w1q = (unsigned short*)d_ws;
    unsigned short* w2q = w1q + 65536;
    float* cst = (float*)(w2q + 65536);   // scale1|bias1|scale2|bias2

    prep_kernel<<<256, 256, 0, stream>>>(w1, w2, b1, g1, be1, m1, v1,
                                         b2, g2, be2, m2, v2, w1q, w2q, cst);
    fused_kernel<<<2048, 256, 0, stream>>>(x, w1q, w2q, cst, (float*)d_out);
}